// Round 5
// baseline (382.172 us; speedup 1.0000x reference)
//
#include <hip/hip_runtime.h>
#include <math.h>

#define N_CL   27
#define C_DIM  384
#define HW_SZ  6400
#define B_SZ   32
#define NPIX   (B_SZ*HW_SZ)        // 204800
#define CHUNK  128
#define ROWW   56                   // [0..26]=nc, [28..54]=clusters, pads at 27/55
#define NBLK_C 400                  // 204800 / (256 threads * 2 px)

// XLA/Eigen fast-tanh f32 (generic_fast_tanh_float), FMA variant:
// clamp |x| to 7.99881172180175781, rational poly, |x|<4e-4 -> x.
__device__ __forceinline__ float xla_tanh_f32(float x) {
    const float c = 7.99881172180175781f;
    if (fabsf(x) < 0.0004f) return x;
    const float xc = fminf(fmaxf(x, -c), c);
    const float x2 = xc*xc;
    float p = fmaf(x2, -2.76076847742355e-16f, 2.00018790482477e-13f);
    p = fmaf(x2, p, -8.60467152213735e-11f);
    p = fmaf(x2, p,  5.12229709037114e-08f);
    p = fmaf(x2, p,  1.48572235717979e-05f);
    p = fmaf(x2, p,  6.37261928875436e-04f);
    p = fmaf(x2, p,  4.89352455891786e-03f);
    p = xc*p;
    float q = fmaf(x2, 1.19825839466702e-06f, 1.18534705686654e-04f);
    q = fmaf(x2, q, 2.26843463243900e-03f);
    q = fmaf(x2, q, 4.89352518554385e-03f);
    return p/q;
}

// ws layout (floats):
//  [0      , 10368) : a   = fast_tanh(3*clusters@w1)
//  [10368  , 20736) : b   = fast_tanh(3*clusters@w2)
//  [20736  , 31104) : cg  = clusters@gcn_w
//  [31104  , 41472) : nc  = normalized refined clusters
//  [41472  , 42272) : per-block partials (2*400)
#define WSF_NC    31104
#define WSF_PARTS 41472

// ---------- kernel A: three 27x384 @ 384x384 matmuls ----------
__global__ __launch_bounds__(384) void cl_refine_mm(const float* __restrict__ clusters,
                                                    const float* __restrict__ w1,
                                                    const float* __restrict__ w2,
                                                    const float* __restrict__ w3,
                                                    float* __restrict__ ws) {
    const int i = blockIdx.x;   // row 0..26
    const int m = blockIdx.y;   // matrix 0..2
    const int j = threadIdx.x;  // col 0..383
    __shared__ float crow[C_DIM];
    crow[j] = clusters[i*C_DIM + j];
    __syncthreads();
    const float* __restrict__ W = (m==0) ? w1 : (m==1) ? w2 : w3;
    float s0=0.f,s1=0.f,s2=0.f,s3=0.f;
    #pragma unroll 4
    for (int k=0;k<C_DIM;k+=4){
        s0 = fmaf(crow[k+0], W[(size_t)(k+0)*C_DIM + j], s0);
        s1 = fmaf(crow[k+1], W[(size_t)(k+1)*C_DIM + j], s1);
        s2 = fmaf(crow[k+2], W[(size_t)(k+2)*C_DIM + j], s2);
        s3 = fmaf(crow[k+3], W[(size_t)(k+3)*C_DIM + j], s3);
    }
    const float acc = (s0+s1)+(s2+s3);
    ws[(size_t)m*N_CL*C_DIM + i*C_DIM + j] = (m<2) ? xla_tanh_f32(3.0f*acc) : acc;
}

// ---------- kernel B: adjacency, top-k, GCN-normalize, cl, nc ----------
__global__ __launch_bounds__(1024) void cl_graph_small(float* __restrict__ ws,
                                                       float* __restrict__ out) {
    const float* __restrict__ Am = ws;
    const float* __restrict__ Bm = ws + N_CL*C_DIM;
    const float* __restrict__ cg = ws + 2*N_CL*C_DIM;
    float* __restrict__ ncw    = ws + WSF_NC;
    float* __restrict__ cl_out = out + 1 + (size_t)NPIX*N_CL;
    const int t = threadIdx.x;

    __shared__ float adj[N_CL][N_CL+1];
    __shared__ float anorm[N_CL][N_CL+1];
    __shared__ float dinv[N_CL];
    __shared__ float rinv[N_CL];
    __shared__ float cls[N_CL][C_DIM];

    if (t < N_CL*N_CL) {
        const int i = t / N_CL, j = t - (t / N_CL)*N_CL;
        const float* ai = Am + (size_t)i*C_DIM;
        const float* bj = Bm + (size_t)j*C_DIM;
        const float* bi = Bm + (size_t)i*C_DIM;
        const float* aj = Am + (size_t)j*C_DIM;
        float p=0.f, q=0.f;
        for (int k=0;k<C_DIM;k++){
            p = fmaf(ai[k], bj[k], p);
            q = fmaf(bi[k], aj[k], q);
        }
        const float m = xla_tanh_f32(3.0f*(p - q));
        adj[i][j] = fmaxf(m, 0.f);        // exact 0 on diagonal (|x|<4e-4 branch)
    }
    __syncthreads();
    if (t < N_CL) {
        // 5th-largest of row t (duplicates counted)
        unsigned mask=0; float thr=0.f;
        for (int s=0;s<5;s++){
            float bv=-1.f; int bi2=0;
            for (int j=0;j<N_CL;j++){
                if (mask & (1u<<j)) continue;
                const float v = adj[t][j];
                if (v > bv){ bv=v; bi2=j; }
            }
            mask |= 1u<<bi2; thr = bv;
        }
        float rs=0.f;
        for (int j=0;j<N_CL;j++){
            float v = adj[t][j];
            v = (v >= thr) ? v : 0.f;
            if (j==t) v += 1.f;           // + eye
            anorm[t][j] = v;
            rs += v;
        }
        dinv[t] = 1.0f / sqrtf(rs);
    }
    __syncthreads();
    if (t < N_CL*N_CL) {
        const int i = t / N_CL, j = t - (t / N_CL)*N_CL;
        anorm[i][j] = dinv[i]*anorm[i][j]*dinv[j];
    }
    __syncthreads();
    for (int idx=t; idx<N_CL*C_DIM; idx+=1024){
        const int i = idx / C_DIM, d = idx - i*C_DIM;
        float s=0.f;
        #pragma unroll
        for (int j=0;j<N_CL;j++) s = fmaf(anorm[i][j], cg[(size_t)j*C_DIM + d], s);
        cls[i][d] = s;
        cl_out[idx] = s;          // output 2: refined clusters
    }
    __syncthreads();
    if (t < N_CL) {
        float ssq=0.f;
        for (int d=0; d<C_DIM; d++){ const float v=cls[t][d]; ssq=fmaf(v,v,ssq); }
        rinv[t] = 1.0f / fmaxf(sqrtf(ssq), 1e-12f);
    }
    __syncthreads();
    for (int idx=t; idx<N_CL*C_DIM; idx+=1024){
        const int i = idx / C_DIM;
        ncw[idx] = cls[i][idx - i*C_DIM] * rinv[i];
    }
}

// ---------- kernel C: fused cosine-sim + softmax loss + entropy, 2 px/thread ----------
__global__ __launch_bounds__(256) void cl_main(const float* __restrict__ x,
                                               const float* __restrict__ alpha_p,
                                               const float* __restrict__ clusters,
                                               float* __restrict__ ws,
                                               float* __restrict__ out) {
    __shared__ float smw[CHUNK][ROWW];
    __shared__ float red[256];
    const float* __restrict__ ncw = ws + WSF_NC;
    const int tid = threadIdx.x;
    const int p0  = (blockIdx.x*256 + tid)*2;       // even, pair never crosses batch
    const int b   = p0 / HW_SZ;
    const int hw  = p0 - b*HW_SZ;
    const float* __restrict__ xb = x + (size_t)b*C_DIM*HW_SZ + hw;

    float a0[N_CL], a1[N_CL], c0[N_CL], c1[N_CL];
    #pragma unroll
    for (int n=0;n<N_CL;n++){ a0[n]=0.f;a1[n]=0.f;c0[n]=0.f;c1[n]=0.f; }
    float ss0=0.f, ss1=0.f;

    for (int ch=0; ch<C_DIM; ch+=CHUNK){
        __syncthreads();
        for (int idx=tid; idx<2*N_CL*CHUNK; idx+=256){
            const int half = idx / (N_CL*CHUNK);
            const int rem  = idx - half*N_CL*CHUNK;
            const int n = rem / CHUNK;
            const int c = rem - n*CHUNK;
            const float* __restrict__ src = half ? clusters : ncw;
            smw[c][half*28 + n] = src[(size_t)n*C_DIM + ch + c];
        }
        __syncthreads();
        #pragma unroll 2
        for (int c=0;c<CHUNK;c++){
            const float2 xv = *(const float2*)(xb + (size_t)(ch+c)*HW_SZ);
            ss0 = fmaf(xv.x,xv.x,ss0);
            ss1 = fmaf(xv.y,xv.y,ss1);
            const float4* r4 = (const float4*)(&smw[c][0]);
            #pragma unroll
            for (int q=0;q<7;q++){
                const float4 wn = r4[q];
                const int n0 = 4*q;
                a0[n0]=fmaf(xv.x,wn.x,a0[n0]); a1[n0]=fmaf(xv.y,wn.x,a1[n0]);
                if (n0+1<N_CL){ a0[n0+1]=fmaf(xv.x,wn.y,a0[n0+1]); a1[n0+1]=fmaf(xv.y,wn.y,a1[n0+1]); }
                if (n0+2<N_CL){ a0[n0+2]=fmaf(xv.x,wn.z,a0[n0+2]); a1[n0+2]=fmaf(xv.y,wn.z,a1[n0+2]); }
                if (n0+3<N_CL){ a0[n0+3]=fmaf(xv.x,wn.w,a0[n0+3]); a1[n0+3]=fmaf(xv.y,wn.w,a1[n0+3]); }
            }
            #pragma unroll
            for (int q=0;q<7;q++){
                const float4 wc = r4[7+q];
                const int n0 = 4*q;
                c0[n0]=fmaf(xv.x,wc.x,c0[n0]); c1[n0]=fmaf(xv.y,wc.x,c1[n0]);
                if (n0+1<N_CL){ c0[n0+1]=fmaf(xv.x,wc.y,c0[n0+1]); c1[n0+1]=fmaf(xv.y,wc.y,c1[n0+1]); }
                if (n0+2<N_CL){ c0[n0+2]=fmaf(xv.x,wc.z,c0[n0+2]); c1[n0+2]=fmaf(xv.y,wc.z,c1[n0+2]); }
                if (n0+3<N_CL){ c0[n0+3]=fmaf(xv.x,wc.w,c0[n0+3]); c1[n0+3]=fmaf(xv.y,wc.w,c1[n0+3]); }
            }
        }
    }

    const float alpha = *alpha_p;
    const float inv0 = 1.0f/fmaxf(sqrtf(ss0),1e-12f);
    const float inv1 = 1.0f/fmaxf(sqrtf(ss1),1e-12f);
    #pragma unroll
    for (int n=0;n<N_CL;n++){ a0[n]*=inv0; a1[n]*=inv1; }

    // output 1: inner_products [B][27][HW]
    float* __restrict__ outp = out + 1 + (size_t)b*N_CL*HW_SZ + hw;
    #pragma unroll
    for (int n=0;n<N_CL;n++){
        float2 v; v.x=a0[n]; v.y=a1[n];
        *(float2*)(outp + (size_t)n*HW_SZ) = v;
    }

    // cluster loss term: sum_n softmax(alpha*ip)[n] * ip[n]
    float m0=-INFINITY, m1=-INFINITY;
    #pragma unroll
    for (int n=0;n<N_CL;n++){ m0=fmaxf(m0, alpha*a0[n]); m1=fmaxf(m1, alpha*a1[n]); }
    float z0=0.f,z1=0.f,t0=0.f,t1=0.f;
    #pragma unroll
    for (int n=0;n<N_CL;n++){
        const float e0=expf(alpha*a0[n]-m0); z0+=e0; t0=fmaf(e0,a0[n],t0);
        const float e1=expf(alpha*a1[n]-m1); z1+=e1; t1=fmaf(e1,a1[n],t1);
    }
    const float pixloss = t0/z0 + t1/z1;

    // entropy of softmax(x·clusters)
    float em0=-INFINITY, em1=-INFINITY;
    #pragma unroll
    for (int n=0;n<N_CL;n++){ em0=fmaxf(em0,c0[n]); em1=fmaxf(em1,c1[n]); }
    float ez0=0.f, ez1=0.f;
    #pragma unroll
    for (int n=0;n<N_CL;n++){ c0[n]=expf(c0[n]-em0); ez0+=c0[n]; c1[n]=expf(c1[n]-em1); ez1+=c1[n]; }
    const float iz0=1.0f/ez0, iz1=1.0f/ez1;
    float ent=0.f;
    #pragma unroll
    for (int n=0;n<N_CL;n++){
        const float pp0=c0[n]*iz0; ent -= pp0*logf(pp0+1e-10f);
        const float pp1=c1[n]*iz1; ent -= pp1*logf(pp1+1e-10f);
    }

    // per-block partial sums (deterministic; no atomics)
    __syncthreads();
    red[tid]=pixloss; __syncthreads();
    for (int s=128;s>0;s>>=1){ if (tid<s) red[tid]+=red[tid+s]; __syncthreads(); }
    float* __restrict__ parts = ws + WSF_PARTS;
    if (tid==0) parts[blockIdx.x] = red[0];
    __syncthreads();
    red[tid]=ent; __syncthreads();
    for (int s=128;s>0;s>>=1){ if (tid<s) red[tid]+=red[tid+s]; __syncthreads(); }
    if (tid==0) parts[NBLK_C + blockIdx.x] = red[0];
}

// ---------- kernel D: final deterministic reduction of the two scalars ----------
__global__ __launch_bounds__(512) void cl_final_reduce(const float* __restrict__ ws,
                                                       float* __restrict__ out) {
    __shared__ float r[512];
    const int t = threadIdx.x;
    const float* parts = ws + WSF_PARTS;
    r[t] = (t<NBLK_C) ? parts[t] : 0.f; __syncthreads();
    for (int s=256;s>0;s>>=1){ if (t<s) r[t]+=r[t+s]; __syncthreads(); }
    if (t==0) out[0] = -r[0]*(1.0f/NPIX);
    __syncthreads();
    r[t] = (t<NBLK_C) ? parts[NBLK_C + t] : 0.f; __syncthreads();
    for (int s=256;s>0;s>>=1){ if (t<s) r[t]+=r[t+s]; __syncthreads(); }
    if (t==0) out[1 + (size_t)NPIX*N_CL + (size_t)N_CL*C_DIM] = r[0]*(1.0f/NPIX);
}

extern "C" void kernel_launch(void* const* d_in, const int* in_sizes, int n_in,
                              void* d_out, int out_size, void* d_ws, size_t ws_size,
                              hipStream_t stream) {
    const float* x        = (const float*)d_in[0];
    const float* alpha    = (const float*)d_in[1];
    const float* clusters = (const float*)d_in[2];
    const float* w1       = (const float*)d_in[3];
    const float* w2       = (const float*)d_in[4];
    const float* w3       = (const float*)d_in[5];
    float* out = (float*)d_out;
    float* ws  = (float*)d_ws;

    cl_refine_mm<<<dim3(27,3), dim3(384), 0, stream>>>(clusters, w1, w2, w3, ws);
    cl_graph_small<<<dim3(1), dim3(1024), 0, stream>>>(ws, out);
    cl_main<<<dim3(NBLK_C), dim3(256), 0, stream>>>(x, alpha, clusters, ws, out);
    cl_final_reduce<<<dim3(1), dim3(512), 0, stream>>>(ws, out);
}

// Round 6
// 351.262 us; speedup vs baseline: 1.0880x; 1.0880x over previous
//
#include <hip/hip_runtime.h>
#include <math.h>

#define N_CL   27
#define C_DIM  384
#define HW_SZ  6400
#define B_SZ   32
#define NPIX   (B_SZ*HW_SZ)        // 204800
#define CHUNK  128
#define ROWW   56                   // [0..26]=nc, [28..54]=clusters, pads at 27/55
#define NBLK_C 800                  // 204800 / (256 threads * 1 px)

// XLA/Eigen fast-tanh f32 (generic_fast_tanh_float), FMA variant:
// clamp |x| to 7.99881172180175781, rational poly, |x|<4e-4 -> x.
__device__ __forceinline__ float xla_tanh_f32(float x) {
    const float c = 7.99881172180175781f;
    if (fabsf(x) < 0.0004f) return x;
    const float xc = fminf(fmaxf(x, -c), c);
    const float x2 = xc*xc;
    float p = fmaf(x2, -2.76076847742355e-16f, 2.00018790482477e-13f);
    p = fmaf(x2, p, -8.60467152213735e-11f);
    p = fmaf(x2, p,  5.12229709037114e-08f);
    p = fmaf(x2, p,  1.48572235717979e-05f);
    p = fmaf(x2, p,  6.37261928875436e-04f);
    p = fmaf(x2, p,  4.89352455891786e-03f);
    p = xc*p;
    float q = fmaf(x2, 1.19825839466702e-06f, 1.18534705686654e-04f);
    q = fmaf(x2, q, 2.26843463243900e-03f);
    q = fmaf(x2, q, 4.89352518554385e-03f);
    return p/q;
}

// ws layout (floats):
//  [0      , 10368) : a   = fast_tanh(3*clusters@w1)
//  [10368  , 20736) : b   = fast_tanh(3*clusters@w2)
//  [20736  , 31104) : cg  = clusters@gcn_w
//  [31104  , 41472) : nc  = normalized refined clusters
//  [41472  , 43072) : per-block partials (2*800)
#define WSF_NC    31104
#define WSF_PARTS 41472

// ---------- kernel A: three 27x384 @ 384x384 matmuls ----------
__global__ __launch_bounds__(384) void cl_refine_mm(const float* __restrict__ clusters,
                                                    const float* __restrict__ w1,
                                                    const float* __restrict__ w2,
                                                    const float* __restrict__ w3,
                                                    float* __restrict__ ws) {
    const int i = blockIdx.x;   // row 0..26
    const int m = blockIdx.y;   // matrix 0..2
    const int j = threadIdx.x;  // col 0..383
    __shared__ float crow[C_DIM];
    crow[j] = clusters[i*C_DIM + j];
    __syncthreads();
    const float* __restrict__ W = (m==0) ? w1 : (m==1) ? w2 : w3;
    float s0=0.f,s1=0.f,s2=0.f,s3=0.f;
    #pragma unroll 4
    for (int k=0;k<C_DIM;k+=4){
        s0 = fmaf(crow[k+0], W[(size_t)(k+0)*C_DIM + j], s0);
        s1 = fmaf(crow[k+1], W[(size_t)(k+1)*C_DIM + j], s1);
        s2 = fmaf(crow[k+2], W[(size_t)(k+2)*C_DIM + j], s2);
        s3 = fmaf(crow[k+3], W[(size_t)(k+3)*C_DIM + j], s3);
    }
    const float acc = (s0+s1)+(s2+s3);
    ws[(size_t)m*N_CL*C_DIM + i*C_DIM + j] = (m<2) ? xla_tanh_f32(3.0f*acc) : acc;
}

// ---------- kernel B: adjacency, top-k, GCN-normalize, cl, nc ----------
__global__ __launch_bounds__(1024) void cl_graph_small(float* __restrict__ ws,
                                                       float* __restrict__ out) {
    const float* __restrict__ Am = ws;
    const float* __restrict__ Bm = ws + N_CL*C_DIM;
    const float* __restrict__ cg = ws + 2*N_CL*C_DIM;
    float* __restrict__ ncw    = ws + WSF_NC;
    float* __restrict__ cl_out = out + 1 + (size_t)NPIX*N_CL;
    const int t = threadIdx.x;

    __shared__ float adj[N_CL][N_CL+1];
    __shared__ float anorm[N_CL][N_CL+1];
    __shared__ float dinv[N_CL];
    __shared__ float rinv[N_CL];
    __shared__ float cls[N_CL][C_DIM];

    if (t < N_CL*N_CL) {
        const int i = t / N_CL, j = t - (t / N_CL)*N_CL;
        const float* ai = Am + (size_t)i*C_DIM;
        const float* bj = Bm + (size_t)j*C_DIM;
        const float* bi = Bm + (size_t)i*C_DIM;
        const float* aj = Am + (size_t)j*C_DIM;
        float p=0.f, q=0.f;
        for (int k=0;k<C_DIM;k++){
            p = fmaf(ai[k], bj[k], p);
            q = fmaf(bi[k], aj[k], q);
        }
        const float m = xla_tanh_f32(3.0f*(p - q));
        adj[i][j] = fmaxf(m, 0.f);        // exact 0 on diagonal (|x|<4e-4 branch)
    }
    __syncthreads();
    if (t < N_CL) {
        // 5th-largest of row t (duplicates counted)
        unsigned mask=0; float thr=0.f;
        for (int s=0;s<5;s++){
            float bv=-1.f; int bi2=0;
            for (int j=0;j<N_CL;j++){
                if (mask & (1u<<j)) continue;
                const float v = adj[t][j];
                if (v > bv){ bv=v; bi2=j; }
            }
            mask |= 1u<<bi2; thr = bv;
        }
        float rs=0.f;
        for (int j=0;j<N_CL;j++){
            float v = adj[t][j];
            v = (v >= thr) ? v : 0.f;
            if (j==t) v += 1.f;           // + eye
            anorm[t][j] = v;
            rs += v;
        }
        dinv[t] = 1.0f / sqrtf(rs);
    }
    __syncthreads();
    if (t < N_CL*N_CL) {
        const int i = t / N_CL, j = t - (t / N_CL)*N_CL;
        anorm[i][j] = dinv[i]*anorm[i][j]*dinv[j];
    }
    __syncthreads();
    for (int idx=t; idx<N_CL*C_DIM; idx+=1024){
        const int i = idx / C_DIM, d = idx - i*C_DIM;
        float s=0.f;
        #pragma unroll
        for (int j=0;j<N_CL;j++) s = fmaf(anorm[i][j], cg[(size_t)j*C_DIM + d], s);
        cls[i][d] = s;
        cl_out[idx] = s;          // output 2: refined clusters
    }
    __syncthreads();
    if (t < N_CL) {
        float ssq=0.f;
        for (int d=0; d<C_DIM; d++){ const float v=cls[t][d]; ssq=fmaf(v,v,ssq); }
        rinv[t] = 1.0f / fmaxf(sqrtf(ssq), 1e-12f);
    }
    __syncthreads();
    for (int idx=t; idx<N_CL*C_DIM; idx+=1024){
        const int i = idx / C_DIM;
        ncw[idx] = cls[i][idx - i*C_DIM] * rinv[i];
    }
}

// ---------- kernel C: fused cosine-sim + softmax loss + entropy, 1 px/thread ----------
__global__ __launch_bounds__(256) void cl_main(const float* __restrict__ x,
                                               const float* __restrict__ alpha_p,
                                               const float* __restrict__ clusters,
                                               float* __restrict__ ws,
                                               float* __restrict__ out) {
    __shared__ float smw[CHUNK][ROWW];
    __shared__ float red[256];
    const float* __restrict__ ncw = ws + WSF_NC;
    const int tid = threadIdx.x;
    const int p   = blockIdx.x*256 + tid;          // 0..204799
    const int b   = p / HW_SZ;
    const int hw  = p - b*HW_SZ;
    const float* __restrict__ xb = x + (size_t)b*C_DIM*HW_SZ + hw;

    float a[N_CL], cc[N_CL];
    #pragma unroll
    for (int n=0;n<N_CL;n++){ a[n]=0.f; cc[n]=0.f; }
    float ss=0.f;

    // 4-deep register prefetch of x down the channel axis
    float xq0 = xb[0*HW_SZ], xq1 = xb[1*HW_SZ], xq2 = xb[2*HW_SZ], xq3 = xb[3*HW_SZ];

    for (int ch=0; ch<C_DIM; ch+=CHUNK){
        __syncthreads();
        for (int idx=tid; idx<2*N_CL*CHUNK; idx+=256){
            const int half = idx / (N_CL*CHUNK);
            const int rem  = idx - half*N_CL*CHUNK;
            const int n = rem / CHUNK;
            const int c = rem - n*CHUNK;
            const float* __restrict__ src = half ? clusters : ncw;
            smw[c][half*28 + n] = src[(size_t)n*C_DIM + ch + c];
        }
        __syncthreads();
        for (int c=0;c<CHUNK;c+=4){
            const float xv0=xq0, xv1=xq1, xv2=xq2, xv3=xq3;
            // prefetch next 4 channels (clamped; extra loads past end are dead)
            const int pf = (ch + c + 4 <= C_DIM-4) ? (ch + c + 4) : (C_DIM-4);
            xq0 = xb[(size_t)(pf+0)*HW_SZ];
            xq1 = xb[(size_t)(pf+1)*HW_SZ];
            xq2 = xb[(size_t)(pf+2)*HW_SZ];
            xq3 = xb[(size_t)(pf+3)*HW_SZ];

            ss = fmaf(xv0,xv0,ss); ss = fmaf(xv1,xv1,ss);
            ss = fmaf(xv2,xv2,ss); ss = fmaf(xv3,xv3,ss);
            #pragma unroll
            for (int u=0;u<4;u++){
                const float xv = (u==0)?xv0:(u==1)?xv1:(u==2)?xv2:xv3;
                const float4* r4 = (const float4*)(&smw[c+u][0]);
                #pragma unroll
                for (int q=0;q<7;q++){
                    const float4 wn = r4[q];
                    const int n0 = 4*q;
                    a[n0]=fmaf(xv,wn.x,a[n0]);
                    if (n0+1<N_CL) a[n0+1]=fmaf(xv,wn.y,a[n0+1]);
                    if (n0+2<N_CL) a[n0+2]=fmaf(xv,wn.z,a[n0+2]);
                    if (n0+3<N_CL) a[n0+3]=fmaf(xv,wn.w,a[n0+3]);
                }
                #pragma unroll
                for (int q=0;q<7;q++){
                    const float4 wc = r4[7+q];
                    const int n0 = 4*q;
                    cc[n0]=fmaf(xv,wc.x,cc[n0]);
                    if (n0+1<N_CL) cc[n0+1]=fmaf(xv,wc.y,cc[n0+1]);
                    if (n0+2<N_CL) cc[n0+2]=fmaf(xv,wc.z,cc[n0+2]);
                    if (n0+3<N_CL) cc[n0+3]=fmaf(xv,wc.w,cc[n0+3]);
                }
            }
        }
    }

    const float alpha = *alpha_p;
    const float inv = 1.0f/fmaxf(sqrtf(ss),1e-12f);
    #pragma unroll
    for (int n=0;n<N_CL;n++) a[n]*=inv;

    // output 1: inner_products [B][27][HW]
    float* __restrict__ outp = out + 1 + (size_t)b*N_CL*HW_SZ + hw;
    #pragma unroll
    for (int n=0;n<N_CL;n++) outp[(size_t)n*HW_SZ] = a[n];

    // cluster loss term: sum_n softmax(alpha*ip)[n] * ip[n]
    float m0=-INFINITY;
    #pragma unroll
    for (int n=0;n<N_CL;n++) m0=fmaxf(m0, alpha*a[n]);
    float z0=0.f,t0=0.f;
    #pragma unroll
    for (int n=0;n<N_CL;n++){
        const float e0=expf(alpha*a[n]-m0); z0+=e0; t0=fmaf(e0,a[n],t0);
    }
    const float pixloss = t0/z0;

    // entropy of softmax(x·clusters)
    float em0=-INFINITY;
    #pragma unroll
    for (int n=0;n<N_CL;n++) em0=fmaxf(em0,cc[n]);
    float ez0=0.f;
    #pragma unroll
    for (int n=0;n<N_CL;n++){ cc[n]=expf(cc[n]-em0); ez0+=cc[n]; }
    const float iz0=1.0f/ez0;
    float ent=0.f;
    #pragma unroll
    for (int n=0;n<N_CL;n++){
        const float pp0=cc[n]*iz0; ent -= pp0*logf(pp0+1e-10f);
    }

    // per-block partial sums (deterministic; no atomics)
    __syncthreads();
    red[tid]=pixloss; __syncthreads();
    for (int s=128;s>0;s>>=1){ if (tid<s) red[tid]+=red[tid+s]; __syncthreads(); }
    float* __restrict__ parts = ws + WSF_PARTS;
    if (tid==0) parts[blockIdx.x] = red[0];
    __syncthreads();
    red[tid]=ent; __syncthreads();
    for (int s=128;s>0;s>>=1){ if (tid<s) red[tid]+=red[tid+s]; __syncthreads(); }
    if (tid==0) parts[NBLK_C + blockIdx.x] = red[0];
}

// ---------- kernel D: final deterministic reduction of the two scalars ----------
__global__ __launch_bounds__(1024) void cl_final_reduce(const float* __restrict__ ws,
                                                        float* __restrict__ out) {
    __shared__ float r[1024];
    const int t = threadIdx.x;
    const float* parts = ws + WSF_PARTS;
    r[t] = (t<NBLK_C) ? parts[t] : 0.f; __syncthreads();
    for (int s=512;s>0;s>>=1){ if (t<s) r[t]+=r[t+s]; __syncthreads(); }
    if (t==0) out[0] = -r[0]*(1.0f/NPIX);
    __syncthreads();
    r[t] = (t<NBLK_C) ? parts[NBLK_C + t] : 0.f; __syncthreads();
    for (int s=512;s>0;s>>=1){ if (t<s) r[t]+=r[t+s]; __syncthreads(); }
    if (t==0) out[1 + (size_t)NPIX*N_CL + (size_t)N_CL*C_DIM] = r[0]*(1.0f/NPIX);
}

extern "C" void kernel_launch(void* const* d_in, const int* in_sizes, int n_in,
                              void* d_out, int out_size, void* d_ws, size_t ws_size,
                              hipStream_t stream) {
    const float* x        = (const float*)d_in[0];
    const float* alpha    = (const float*)d_in[1];
    const float* clusters = (const float*)d_in[2];
    const float* w1       = (const float*)d_in[3];
    const float* w2       = (const float*)d_in[4];
    const float* w3       = (const float*)d_in[5];
    float* out = (float*)d_out;
    float* ws  = (float*)d_ws;

    cl_refine_mm<<<dim3(27,3), dim3(384), 0, stream>>>(clusters, w1, w2, w3, ws);
    cl_graph_small<<<dim3(1), dim3(1024), 0, stream>>>(ws, out);
    cl_main<<<dim3(NBLK_C), dim3(256), 0, stream>>>(x, alpha, clusters, ws, out);
    cl_final_reduce<<<dim3(1), dim3(1024), 0, stream>>>(ws, out);
}

// Round 8
// 310.555 us; speedup vs baseline: 1.2306x; 1.1311x over previous
//
#include <hip/hip_runtime.h>
#include <math.h>

#define N_CL   27
#define C_DIM  384
#define HW_SZ  6400
#define B_SZ   32
#define NPIX   (B_SZ*HW_SZ)        // 204800
#define NTILE  3200                 // 64-px tiles
#define WSF_PARTS 24576             // float offset of per-tile partials (2*3200)
#define ENT_OFF (1 + (size_t)NPIX*N_CL + (size_t)N_CL*C_DIM)

typedef unsigned short ushort_t;
using bf16x8 = __attribute__((ext_vector_type(8))) short;
using f32x4  = __attribute__((ext_vector_type(4))) float;

// XLA/Eigen fast-tanh f32 (FMA variant) — matches jax f32 reference semantics
__device__ __forceinline__ float xla_tanh_f32(float x) {
    const float c = 7.99881172180175781f;
    if (fabsf(x) < 0.0004f) return x;
    const float xc = fminf(fmaxf(x, -c), c);
    const float x2 = xc*xc;
    float p = fmaf(x2, -2.76076847742355e-16f, 2.00018790482477e-13f);
    p = fmaf(x2, p, -8.60467152213735e-11f);
    p = fmaf(x2, p,  5.12229709037114e-08f);
    p = fmaf(x2, p,  1.48572235717979e-05f);
    p = fmaf(x2, p,  6.37261928875436e-04f);
    p = fmaf(x2, p,  4.89352455891786e-03f);
    p = xc*p;
    float q = fmaf(x2, 1.19825839466702e-06f, 1.18534705686654e-04f);
    q = fmaf(x2, q, 2.26843463243900e-03f);
    q = fmaf(x2, q, 4.89352518554385e-03f);
    return p/q;
}

// ---------- kernel A: three 27x384 @ 384x384 matmuls (f32, unchanged numerics) ----------
__global__ __launch_bounds__(384) void cl_refine_mm(const float* __restrict__ clusters,
                                                    const float* __restrict__ w1,
                                                    const float* __restrict__ w2,
                                                    const float* __restrict__ w3,
                                                    float* __restrict__ ws) {
    const int i = blockIdx.x;
    const int m = blockIdx.y;
    const int j = threadIdx.x;
    __shared__ float crow[C_DIM];
    crow[j] = clusters[i*C_DIM + j];
    __syncthreads();
    const float* __restrict__ W = (m==0) ? w1 : (m==1) ? w2 : w3;
    float s0=0.f,s1=0.f,s2=0.f,s3=0.f;
    #pragma unroll 4
    for (int k=0;k<C_DIM;k+=4){
        s0 = fmaf(crow[k+0], W[(size_t)(k+0)*C_DIM + j], s0);
        s1 = fmaf(crow[k+1], W[(size_t)(k+1)*C_DIM + j], s1);
        s2 = fmaf(crow[k+2], W[(size_t)(k+2)*C_DIM + j], s2);
        s3 = fmaf(crow[k+3], W[(size_t)(k+3)*C_DIM + j], s3);
    }
    const float acc = (s0+s1)+(s2+s3);
    ws[(size_t)m*N_CL*C_DIM + i*C_DIM + j] = (m<2) ? xla_tanh_f32(3.0f*acc) : acc;
}

// ---------- kernel B: adjacency, top-k, GCN, cl; then pack W (bf16 hi/lo) ----------
__global__ __launch_bounds__(1024) void cl_graph_small(float* ws,
                                                       const float* __restrict__ clusters_g,
                                                       float* __restrict__ out) {
    const float* Am = ws;
    const float* Bm = ws + N_CL*C_DIM;
    const float* cg = ws + 2*N_CL*C_DIM;
    float* cl_out = out + 1 + (size_t)NPIX*N_CL;
    const int t = threadIdx.x;

    __shared__ float adj[N_CL][N_CL+1];
    __shared__ float anorm[N_CL][N_CL+1];
    __shared__ float dinv[N_CL];
    __shared__ float rinv[N_CL];
    __shared__ float cls[N_CL][C_DIM];

    if (t < N_CL*N_CL) {
        const int i = t / N_CL, j = t - (t / N_CL)*N_CL;
        const float* ai = Am + (size_t)i*C_DIM;
        const float* bj = Bm + (size_t)j*C_DIM;
        const float* bi = Bm + (size_t)i*C_DIM;
        const float* aj = Am + (size_t)j*C_DIM;
        float p=0.f, q=0.f;
        for (int k=0;k<C_DIM;k++){
            p = fmaf(ai[k], bj[k], p);
            q = fmaf(bi[k], aj[k], q);
        }
        const float m = xla_tanh_f32(3.0f*(p - q));
        adj[i][j] = fmaxf(m, 0.f);
    }
    __syncthreads();
    if (t < N_CL) {
        unsigned mask=0; float thr=0.f;
        for (int s=0;s<5;s++){
            float bv=-1.f; int bi2=0;
            for (int j=0;j<N_CL;j++){
                if (mask & (1u<<j)) continue;
                const float v = adj[t][j];
                if (v > bv){ bv=v; bi2=j; }
            }
            mask |= 1u<<bi2; thr = bv;
        }
        float rs=0.f;
        for (int j=0;j<N_CL;j++){
            float v = adj[t][j];
            v = (v >= thr) ? v : 0.f;
            if (j==t) v += 1.f;
            anorm[t][j] = v;
            rs += v;
        }
        dinv[t] = 1.0f / sqrtf(rs);
    }
    __syncthreads();
    if (t < N_CL*N_CL) {
        const int i = t / N_CL, j = t - (t / N_CL)*N_CL;
        anorm[i][j] = dinv[i]*anorm[i][j]*dinv[j];
    }
    __syncthreads();
    for (int idx=t; idx<N_CL*C_DIM; idx+=1024){
        const int i = idx / C_DIM, d = idx - i*C_DIM;
        float s=0.f;
        #pragma unroll
        for (int j=0;j<N_CL;j++) s = fmaf(anorm[i][j], cg[(size_t)j*C_DIM + d], s);
        cls[i][d] = s;
        cl_out[idx] = s;          // output 2: refined clusters
    }
    __syncthreads();
    if (t < N_CL) {
        float ssq=0.f;
        for (int d=0; d<C_DIM; d++){ const float v=cls[t][d]; ssq=fmaf(v,v,ssq); }
        rinv[t] = 1.0f / fmaxf(sqrtf(ssq), 1e-12f);
    }
    __syncthreads();
    // Pack weights: n<27 = normalized cl rows; 32<=n<59 = raw clusters; else 0.
    // hi = truncate-to-bf16(v); lo = bf16(v - hi). Overwrites a/b/cg region (done with).
    ushort_t* wpk = (ushort_t*)ws;
    for (int idx=t; idx<64*C_DIM; idx+=1024){
        const int n = idx / C_DIM, k = idx - n*C_DIM;
        float v = 0.f;
        if (n < N_CL) v = cls[n][k] * rinv[n];
        else if (n >= 32 && n < 32+N_CL) v = clusters_g[(size_t)(n-32)*C_DIM + k];
        const unsigned bits = __float_as_uint(v);
        const ushort_t hi = (ushort_t)(bits >> 16);
        const float lof = v - __uint_as_float(bits & 0xFFFF0000u);
        const ushort_t lo = (ushort_t)(__float_as_uint(lof) >> 16);
        wpk[idx] = hi;
        wpk[64*C_DIM + idx] = lo;
    }
}

// ---------- kernel C: split-bf16 MFMA GEMM + fused softmax loss / entropy ----------
__global__ __launch_bounds__(256, 6) void cl_mfma(const float* __restrict__ x,
                                                  const float* __restrict__ alpha_p,
                                                  const ushort_t* __restrict__ wpk,
                                                  float* __restrict__ ws,
                                                  float* __restrict__ out) {
    __shared__ __align__(16) float    lA[64][36];       // [px][k] padded
    __shared__ __align__(16) ushort_t lB[2][64][40];    // [hi/lo][n][k] padded
    __shared__ float redL[4], redE[4];

    const int tid = threadIdx.x;
    const int blk = blockIdx.x;
    const int b   = blk / 100;
    const int hw0 = (blk - b*100) * 64;
    const float* __restrict__ xb = x + (size_t)b*C_DIM*HW_SZ + hw0;

    const int lane = tid & 63;
    const int w    = tid >> 6;
    const int l15  = lane & 15;
    const int g    = lane >> 4;
    const int k0   = g*8;
    const int apx  = w*16 + l15;

    f32x4 acc0={0,0,0,0}, acc1={0,0,0,0}, acc2={0,0,0,0}, acc3={0,0,0,0};
    float ss = 0.f;

    for (int ch = 0; ch < C_DIM; ch += 32) {
        __syncthreads();
        #pragma unroll
        for (int i = 0; i < 8; i++) {            // stage A: 64px x 32k f32
            const int idx = i*256 + tid;
            const int kk = idx >> 6;
            const int px = idx & 63;
            lA[px][kk] = xb[(size_t)(ch + kk)*HW_SZ + px];
        }
        #pragma unroll
        for (int i = 0; i < 2; i++) {            // stage B: 2 x 64n x 32k bf16
            const int idx = i*256 + tid;
            const int h  = idx >> 8;
            const int n  = (idx & 255) >> 2;
            const int kb = (idx & 3) * 8;
            const uint4 v = *(const uint4*)(wpk + ((size_t)(h*64 + n)*C_DIM + ch + kb));
            *(uint4*)(&lB[h][n][kb]) = v;
        }
        __syncthreads();
        // A fragment: 8 f32 -> bf16 hi/lo, accumulate ss from exact f32
        const f32x4 a0 = *(const f32x4*)(&lA[apx][k0]);
        const f32x4 a1 = *(const f32x4*)(&lA[apx][k0+4]);
        union { ushort_t u[8]; bf16x8 v; } Ah, Al;
        #pragma unroll
        for (int e = 0; e < 8; e++) {
            const float xv = (e<4) ? a0[e] : a1[e-4];
            const unsigned bits = __float_as_uint(xv);
            Ah.u[e] = (ushort_t)(bits >> 16);
            const float lof = xv - __uint_as_float(bits & 0xFFFF0000u);
            Al.u[e] = (ushort_t)(__float_as_uint(lof) >> 16);
            ss = fmaf(xv, xv, ss);
        }
        #pragma unroll
        for (int t = 0; t < 4; t++) {
            union { uint4 q; bf16x8 v; } Bh, Bl;
            Bh.q = *(const uint4*)(&lB[0][t*16 + l15][k0]);
            Bl.q = *(const uint4*)(&lB[1][t*16 + l15][k0]);
            f32x4 a;
            a = (t==0)?acc0:(t==1)?acc1:(t==2)?acc2:acc3;
            a = __builtin_amdgcn_mfma_f32_16x16x32_bf16(Ah.v, Bh.v, a, 0,0,0);
            a = __builtin_amdgcn_mfma_f32_16x16x32_bf16(Ah.v, Bl.v, a, 0,0,0);
            a = __builtin_amdgcn_mfma_f32_16x16x32_bf16(Al.v, Bh.v, a, 0,0,0);
            if (t==0) acc0=a; else if (t==1) acc1=a; else if (t==2) acc2=a; else acc3=a;
        }
    }

    // full ||x||^2 per px (combine 4 k-slice groups; lanes with same l15 share px)
    ss += __shfl_xor(ss, 16);
    ss += __shfl_xor(ss, 32);
    f32x4 invv;
    #pragma unroll
    for (int r = 0; r < 4; r++) {
        const float s2 = __shfl(ss, g*4 + r);    // lane l15==g*4+r holds ss for that px
        invv[r] = 1.0f / fmaxf(sqrtf(s2), 1e-12f);
    }

    const float alpha = alpha_p[0];
    float* __restrict__ out1 = out + 1;
    const int pxb = hw0 + w*16 + g*4;

    f32x4 st0, st1;
    #pragma unroll
    for (int r=0;r<4;r++){ st0[r] = acc0[r]*invv[r]; st1[r] = acc1[r]*invv[r]; }
    *(f32x4*)(out1 + (size_t)b*N_CL*HW_SZ + (size_t)l15*HW_SZ + pxb) = st0;
    if (l15 <= 10)
        *(f32x4*)(out1 + (size_t)b*N_CL*HW_SZ + (size_t)(16+l15)*HW_SZ + pxb) = st1;

    float wloss = 0.f, went = 0.f;
    #pragma unroll
    for (int r=0;r<4;r++){
        // cluster-loss softmax over 27 cosine sims
        const float ip0 = st0[r], ip1 = st1[r];
        const float v0 = alpha*ip0;
        const float v1 = (l15<=10) ? alpha*ip1 : -INFINITY;
        float mx = fmaxf(v0, v1);
        #pragma unroll
        for (int m=1;m<16;m<<=1) mx = fmaxf(mx, __shfl_xor(mx, m));
        const float e0 = expf(v0 - mx);
        const float e1 = (l15<=10) ? expf(v1 - mx) : 0.f;
        float z = e0 + e1;
        float tt = fmaf(e0, ip0, (l15<=10) ? e1*ip1 : 0.f);
        #pragma unroll
        for (int m=1;m<16;m<<=1){ z += __shfl_xor(z,m); tt += __shfl_xor(tt,m); }
        wloss += tt/z;
        // entropy of softmax(x . clusters)
        const float c0 = acc2[r];
        const float c1 = (l15<=10) ? acc3[r] : -INFINITY;
        float emx = fmaxf(c0, c1);
        #pragma unroll
        for (int m=1;m<16;m<<=1) emx = fmaxf(emx, __shfl_xor(emx, m));
        const float f0 = expf(c0 - emx);
        const float f1 = (l15<=10) ? expf(c1 - emx) : 0.f;
        float ez = f0 + f1;
        #pragma unroll
        for (int m=1;m<16;m<<=1) ez += __shfl_xor(ez,m);
        const float iz = 1.0f/ez;
        const float p0 = f0*iz, p1 = f1*iz;
        float te = -p0*logf(p0+1e-10f) - p1*logf(p1+1e-10f);
        #pragma unroll
        for (int m=1;m<16;m<<=1) te += __shfl_xor(te,m);
        went += te;
    }
    // wave total: after the xor-16/32 chain each group's (already uniform)
    // value is added exactly ONCE per lane -> no /16.
    wloss += __shfl_xor(wloss,16); wloss += __shfl_xor(wloss,32);
    went  += __shfl_xor(went ,16); went  += __shfl_xor(went ,32);
    if (lane == 0) { redL[w] = wloss; redE[w] = went; }
    __syncthreads();
    if (tid == 0) {
        float* parts = ws + WSF_PARTS;
        parts[blk]         = redL[0]+redL[1]+redL[2]+redL[3];
        parts[NTILE + blk] = redE[0]+redE[1]+redE[2]+redE[3];
    }
}

// ---------- kernel D: final deterministic reduction ----------
__global__ __launch_bounds__(1024) void cl_final_reduce(const float* __restrict__ ws,
                                                        float* __restrict__ out) {
    __shared__ float r[1024];
    const int t = threadIdx.x;
    const float* parts = ws + WSF_PARTS;
    float s = 0.f;
    for (int j=t; j<NTILE; j+=1024) s += parts[j];
    r[t] = s; __syncthreads();
    for (int sft=512;sft>0;sft>>=1){ if (t<sft) r[t]+=r[t+sft]; __syncthreads(); }
    if (t==0) out[0] = -r[0]*(1.0f/NPIX);
    __syncthreads();
    s = 0.f;
    for (int j=t; j<NTILE; j+=1024) s += parts[NTILE + j];
    r[t] = s; __syncthreads();
    for (int sft=512;sft>0;sft>>=1){ if (t<sft) r[t]+=r[t+sft]; __syncthreads(); }
    if (t==0) out[ENT_OFF] = r[0]*(1.0f/NPIX);
}

extern "C" void kernel_launch(void* const* d_in, const int* in_sizes, int n_in,
                              void* d_out, int out_size, void* d_ws, size_t ws_size,
                              hipStream_t stream) {
    const float* x        = (const float*)d_in[0];
    const float* alpha    = (const float*)d_in[1];
    const float* clusters = (const float*)d_in[2];
    const float* w1       = (const float*)d_in[3];
    const float* w2       = (const float*)d_in[4];
    const float* w3       = (const float*)d_in[5];
    float* out = (float*)d_out;
    float* ws  = (float*)d_ws;

    cl_refine_mm<<<dim3(27,3), dim3(384), 0, stream>>>(clusters, w1, w2, w3, ws);
    cl_graph_small<<<dim3(1), dim3(1024), 0, stream>>>(ws, clusters, out);
    cl_mfma<<<dim3(NTILE), dim3(256), 0, stream>>>(x, alpha, (const ushort_t*)ws, ws, out);
    cl_final_reduce<<<dim3(1), dim3(1024), 0, stream>>>(ws, out);
}

// Round 9
// 136.912 us; speedup vs baseline: 2.7914x; 2.2683x over previous
//
#include <hip/hip_runtime.h>
#include <math.h>

#define N_CL   27
#define C_DIM  384
#define HW_SZ  6400
#define B_SZ   32
#define NPIX   (B_SZ*HW_SZ)        // 204800
#define NTILE  3200                 // 64-px tiles
#define NCHUNK 12                   // 384/32
#define WSF_PARTS 24576             // parts: [24576, 24576+6400)
#define WSF_ADJ   40000             // adj:   [40000, 40729)
#define ENT_OFF (1 + (size_t)NPIX*N_CL + (size_t)N_CL*C_DIM)

typedef unsigned short ushort_t;
using bf16x8 = __attribute__((ext_vector_type(8))) short;
using f32x4  = __attribute__((ext_vector_type(4))) float;

// XLA/Eigen fast-tanh f32 (FMA variant) — matches jax f32 reference semantics
__device__ __forceinline__ float xla_tanh_f32(float x) {
    const float c = 7.99881172180175781f;
    if (fabsf(x) < 0.0004f) return x;
    const float xc = fminf(fmaxf(x, -c), c);
    const float x2 = xc*xc;
    float p = fmaf(x2, -2.76076847742355e-16f, 2.00018790482477e-13f);
    p = fmaf(x2, p, -8.60467152213735e-11f);
    p = fmaf(x2, p,  5.12229709037114e-08f);
    p = fmaf(x2, p,  1.48572235717979e-05f);
    p = fmaf(x2, p,  6.37261928875436e-04f);
    p = fmaf(x2, p,  4.89352455891786e-03f);
    p = xc*p;
    float q = fmaf(x2, 1.19825839466702e-06f, 1.18534705686654e-04f);
    q = fmaf(x2, q, 2.26843463243900e-03f);
    q = fmaf(x2, q, 4.89352518554385e-03f);
    return p/q;
}

// ---------- kernel A: three 27x384 @ 384x384 matmuls ----------
__global__ __launch_bounds__(384) void cl_refine_mm(const float* __restrict__ clusters,
                                                    const float* __restrict__ w1,
                                                    const float* __restrict__ w2,
                                                    const float* __restrict__ w3,
                                                    float* __restrict__ ws) {
    const int i = blockIdx.x;
    const int m = blockIdx.y;
    const int j = threadIdx.x;
    __shared__ float crow[C_DIM];
    crow[j] = clusters[i*C_DIM + j];
    __syncthreads();
    const float* __restrict__ W = (m==0) ? w1 : (m==1) ? w2 : w3;
    float s0=0.f,s1=0.f,s2=0.f,s3=0.f;
    #pragma unroll 4
    for (int k=0;k<C_DIM;k+=4){
        s0 = fmaf(crow[k+0], W[(size_t)(k+0)*C_DIM + j], s0);
        s1 = fmaf(crow[k+1], W[(size_t)(k+1)*C_DIM + j], s1);
        s2 = fmaf(crow[k+2], W[(size_t)(k+2)*C_DIM + j], s2);
        s3 = fmaf(crow[k+3], W[(size_t)(k+3)*C_DIM + j], s3);
    }
    const float acc = (s0+s1)+(s2+s3);
    ws[(size_t)m*N_CL*C_DIM + i*C_DIM + j] = (m<2) ? xla_tanh_f32(3.0f*acc) : acc;
}

// ---------- kernel A2: adjacency entries, one (i,j) per 1-wave block ----------
__global__ __launch_bounds__(64) void cl_adj(const float* __restrict__ ws,
                                             float* __restrict__ adj_out) {
    const float* __restrict__ Am = ws;
    const float* __restrict__ Bm = ws + N_CL*C_DIM;
    const int i = blockIdx.x / N_CL, j = blockIdx.x - (blockIdx.x / N_CL)*N_CL;
    const int lane = threadIdx.x;
    float p=0.f, q=0.f;
    #pragma unroll
    for (int e=0;e<6;e++){
        const int k = e*64 + lane;
        p = fmaf(Am[i*C_DIM+k], Bm[j*C_DIM+k], p);
        q = fmaf(Bm[i*C_DIM+k], Am[j*C_DIM+k], q);
    }
    float d = p - q;     // i==j: p==q per-lane (identical order) -> exact 0
    #pragma unroll
    for (int m=1;m<64;m<<=1) d += __shfl_xor(d, m);
    if (lane==0) adj_out[blockIdx.x] = fmaxf(xla_tanh_f32(3.0f*d), 0.f);
}

// ---------- kernel B: top-k, GCN normalize, cl; pack W (bf16 hi/lo) ----------
__global__ __launch_bounds__(1024) void cl_graph2(float* ws,
                                                  const float* __restrict__ clusters_g,
                                                  float* __restrict__ out) {
    const float* cg = ws + 2*N_CL*C_DIM;
    float* cl_out = out + 1 + (size_t)NPIX*N_CL;
    const int t = threadIdx.x;

    __shared__ float anorm[N_CL][N_CL+1];
    __shared__ float dinv[N_CL];
    __shared__ float rinv[N_CL];
    __shared__ float cls[N_CL][C_DIM];

    if (t < N_CL*N_CL) {
        const int i = t / N_CL, j = t - (t / N_CL)*N_CL;
        anorm[i][j] = ws[WSF_ADJ + t];
    }
    __syncthreads();
    if (t < N_CL) {
        unsigned mask=0; float thr=0.f;
        for (int s=0;s<5;s++){
            float bv=-1.f; int bi2=0;
            for (int j=0;j<N_CL;j++){
                if (mask & (1u<<j)) continue;
                const float v = anorm[t][j];
                if (v > bv){ bv=v; bi2=j; }
            }
            mask |= 1u<<bi2; thr = bv;
        }
        float rs=0.f;
        for (int j=0;j<N_CL;j++){
            float v = anorm[t][j];
            v = (v >= thr) ? v : 0.f;
            if (j==t) v += 1.f;
            anorm[t][j] = v;
            rs += v;
        }
        dinv[t] = 1.0f / sqrtf(rs);
    }
    __syncthreads();
    if (t < N_CL*N_CL) {
        const int i = t / N_CL, j = t - (t / N_CL)*N_CL;
        anorm[i][j] = dinv[i]*anorm[i][j]*dinv[j];
    }
    __syncthreads();
    for (int idx=t; idx<N_CL*C_DIM; idx+=1024){
        const int i = idx / C_DIM, d = idx - i*C_DIM;
        float s=0.f;
        #pragma unroll
        for (int j=0;j<N_CL;j++) s = fmaf(anorm[i][j], cg[(size_t)j*C_DIM + d], s);
        cls[i][d] = s;
        cl_out[idx] = s;          // output 2: refined clusters
    }
    __syncthreads();
    if (t < N_CL) {
        float ssq=0.f;
        for (int d=0; d<C_DIM; d++){ const float v=cls[t][d]; ssq=fmaf(v,v,ssq); }
        rinv[t] = 1.0f / fmaxf(sqrtf(ssq), 1e-12f);
    }
    __syncthreads();
    // Pack: n<27 = normalized cl rows; 32<=n<59 = raw clusters; else 0.
    ushort_t* wpk = (ushort_t*)ws;
    for (int idx=t; idx<64*C_DIM; idx+=1024){
        const int n = idx / C_DIM, k = idx - n*C_DIM;
        float v = 0.f;
        if (n < N_CL) v = cls[n][k] * rinv[n];
        else if (n >= 32 && n < 32+N_CL) v = clusters_g[(size_t)(n-32)*C_DIM + k];
        const unsigned bits = __float_as_uint(v);
        const ushort_t hi = (ushort_t)(bits >> 16);
        const float lof = v - __uint_as_float(bits & 0xFFFF0000u);
        const ushort_t lo = (ushort_t)(__float_as_uint(lof) >> 16);
        wpk[idx] = hi;
        wpk[64*C_DIM + idx] = lo;
    }
}

// ---------- kernel C: pipelined split-bf16 MFMA GEMM + fused loss/entropy ----------
__global__ __launch_bounds__(256, 4) void cl_mfma(const float* __restrict__ x,
                                                  const float* __restrict__ alpha_p,
                                                  const ushort_t* __restrict__ wpk,
                                                  float* __restrict__ ws,
                                                  float* __restrict__ out) {
    __shared__ float    lA[2][64][33];                  // [buf][px][k] (b32, conflict-free)
    __shared__ __align__(16) ushort_t lB[2][2][64][40]; // [buf][hi/lo][n][k]
    __shared__ float redL[4], redE[4];

    const int tid = threadIdx.x;
    const int blk = blockIdx.x;
    const int b   = blk / 100;
    const int hw0 = (blk - b*100) * 64;
    const float* __restrict__ xb = x + (size_t)b*C_DIM*HW_SZ + hw0;

    const int lane = tid & 63;
    const int w    = tid >> 6;
    const int l15  = lane & 15;
    const int g    = lane >> 4;
    const int k0   = g*8;
    const int apx  = w*16 + l15;

    // staging decomposition
    const int a_kk = tid >> 4;           // 0..15 (j adds +16)
    const int a_px = (tid & 15) * 4;
    const int b_n  = tid >> 2;           // 0..63
    const int b_kb = (tid & 3) * 8;

    float4 ra0, ra1; uint4 rb0, rb1;
    #define LOADR(c) {                                                            \
        const int ch = (c)*32;                                                    \
        ra0 = *(const float4*)(xb + (size_t)(ch      + a_kk)*HW_SZ + a_px);       \
        ra1 = *(const float4*)(xb + (size_t)(ch + 16 + a_kk)*HW_SZ + a_px);       \
        rb0 = *(const uint4*)(wpk + (size_t)(     b_n)*C_DIM + ch + b_kb);        \
        rb1 = *(const uint4*)(wpk + (size_t)(64 + b_n)*C_DIM + ch + b_kb); }
    #define WRITE(bf) {                                                           \
        lA[bf][a_px+0][a_kk]    = ra0.x; lA[bf][a_px+1][a_kk]    = ra0.y;         \
        lA[bf][a_px+2][a_kk]    = ra0.z; lA[bf][a_px+3][a_kk]    = ra0.w;         \
        lA[bf][a_px+0][a_kk+16] = ra1.x; lA[bf][a_px+1][a_kk+16] = ra1.y;         \
        lA[bf][a_px+2][a_kk+16] = ra1.z; lA[bf][a_px+3][a_kk+16] = ra1.w;         \
        *(uint4*)(&lB[bf][0][b_n][b_kb]) = rb0;                                   \
        *(uint4*)(&lB[bf][1][b_n][b_kb]) = rb1; }

    f32x4 acc0={0,0,0,0}, acc1={0,0,0,0}, acc2={0,0,0,0}, acc3={0,0,0,0};
    float ss = 0.f;

    LOADR(0);
    WRITE(0);
    LOADR(1);
    __syncthreads();

    for (int c = 0; c < NCHUNK; c++) {
        const int cur = c & 1;
        // A fragment: 8 f32 from LDS -> bf16 hi/lo; ss from exact f32
        union { ushort_t u[8]; bf16x8 v; } Ah, Al;
        #pragma unroll
        for (int e = 0; e < 8; e++) {
            const float xv = lA[cur][apx][k0 + e];
            const unsigned bits = __float_as_uint(xv);
            Ah.u[e] = (ushort_t)(bits >> 16);
            const float lof = xv - __uint_as_float(bits & 0xFFFF0000u);
            Al.u[e] = (ushort_t)(__float_as_uint(lof) >> 16);
            ss = fmaf(xv, xv, ss);
        }
        #pragma unroll
        for (int t = 0; t < 4; t++) {
            union { uint4 q; bf16x8 v; } Bh, Bl;
            Bh.q = *(const uint4*)(&lB[cur][0][t*16 + l15][k0]);
            Bl.q = *(const uint4*)(&lB[cur][1][t*16 + l15][k0]);
            f32x4 a;
            a = (t==0)?acc0:(t==1)?acc1:(t==2)?acc2:acc3;
            a = __builtin_amdgcn_mfma_f32_16x16x32_bf16(Ah.v, Bh.v, a, 0,0,0);
            a = __builtin_amdgcn_mfma_f32_16x16x32_bf16(Ah.v, Bl.v, a, 0,0,0);
            a = __builtin_amdgcn_mfma_f32_16x16x32_bf16(Al.v, Bh.v, a, 0,0,0);
            if (t==0) acc0=a; else if (t==1) acc1=a; else if (t==2) acc2=a; else acc3=a;
        }
        __syncthreads();
        if (c + 1 < NCHUNK) {
            WRITE(cur ^ 1);                 // vmcnt wait for LOADR(c+1) regs
            if (c + 2 < NCHUNK) LOADR(c+2); // issue next; in flight across barrier
            __syncthreads();
        }
    }

    // full ||x||^2 per px
    ss += __shfl_xor(ss, 16);
    ss += __shfl_xor(ss, 32);
    f32x4 invv;
    #pragma unroll
    for (int r = 0; r < 4; r++) {
        const float s2 = __shfl(ss, g*4 + r);
        invv[r] = 1.0f / fmaxf(sqrtf(s2), 1e-12f);
    }

    const float alpha = alpha_p[0];
    float* __restrict__ out1 = out + 1;
    const int pxb = hw0 + w*16 + g*4;

    f32x4 st0, st1;
    #pragma unroll
    for (int r=0;r<4;r++){ st0[r] = acc0[r]*invv[r]; st1[r] = acc1[r]*invv[r]; }
    *(f32x4*)(out1 + (size_t)b*N_CL*HW_SZ + (size_t)l15*HW_SZ + pxb) = st0;
    if (l15 <= 10)
        *(f32x4*)(out1 + (size_t)b*N_CL*HW_SZ + (size_t)(16+l15)*HW_SZ + pxb) = st1;

    float wloss = 0.f, went = 0.f;
    #pragma unroll
    for (int r=0;r<4;r++){
        const float ip0 = st0[r], ip1 = st1[r];
        const float v0 = alpha*ip0;
        const float v1 = (l15<=10) ? alpha*ip1 : -INFINITY;
        float mx = fmaxf(v0, v1);
        #pragma unroll
        for (int m=1;m<16;m<<=1) mx = fmaxf(mx, __shfl_xor(mx, m));
        const float e0 = expf(v0 - mx);
        const float e1 = (l15<=10) ? expf(v1 - mx) : 0.f;
        float z = e0 + e1;
        float tt = fmaf(e0, ip0, (l15<=10) ? e1*ip1 : 0.f);
        #pragma unroll
        for (int m=1;m<16;m<<=1){ z += __shfl_xor(z,m); tt += __shfl_xor(tt,m); }
        wloss += tt/z;
        const float c0 = acc2[r];
        const float c1 = (l15<=10) ? acc3[r] : -INFINITY;
        float emx = fmaxf(c0, c1);
        #pragma unroll
        for (int m=1;m<16;m<<=1) emx = fmaxf(emx, __shfl_xor(emx, m));
        const float f0 = expf(c0 - emx);
        const float f1 = (l15<=10) ? expf(c1 - emx) : 0.f;
        float ez = f0 + f1;
        #pragma unroll
        for (int m=1;m<16;m<<=1) ez += __shfl_xor(ez,m);
        const float iz = 1.0f/ez;
        const float p0 = f0*iz, p1 = f1*iz;
        float te = -p0*logf(p0+1e-10f) - p1*logf(p1+1e-10f);
        #pragma unroll
        for (int m=1;m<16;m<<=1) te += __shfl_xor(te,m);
        went += te;
    }
    wloss += __shfl_xor(wloss,16); wloss += __shfl_xor(wloss,32);
    went  += __shfl_xor(went ,16); went  += __shfl_xor(went ,32);
    if (lane == 0) { redL[w] = wloss; redE[w] = went; }
    __syncthreads();
    if (tid == 0) {
        float* parts = ws + WSF_PARTS;
        parts[blk]         = redL[0]+redL[1]+redL[2]+redL[3];
        parts[NTILE + blk] = redE[0]+redE[1]+redE[2]+redE[3];
    }
}

// ---------- kernel D: final deterministic reduction ----------
__global__ __launch_bounds__(1024) void cl_final_reduce(const float* __restrict__ ws,
                                                        float* __restrict__ out) {
    __shared__ float r[1024];
    const int t = threadIdx.x;
    const float* parts = ws + WSF_PARTS;
    float s = 0.f;
    for (int j=t; j<NTILE; j+=1024) s += parts[j];
    r[t] = s; __syncthreads();
    for (int sft=512;sft>0;sft>>=1){ if (t<sft) r[t]+=r[t+sft]; __syncthreads(); }
    if (t==0) out[0] = -r[0]*(1.0f/NPIX);
    __syncthreads();
    s = 0.f;
    for (int j=t; j<NTILE; j+=1024) s += parts[NTILE + j];
    r[t] = s; __syncthreads();
    for (int sft=512;sft>0;sft>>=1){ if (t<sft) r[t]+=r[t+sft]; __syncthreads(); }
    if (t==0) out[ENT_OFF] = r[0]*(1.0f/NPIX);
}

extern "C" void kernel_launch(void* const* d_in, const int* in_sizes, int n_in,
                              void* d_out, int out_size, void* d_ws, size_t ws_size,
                              hipStream_t stream) {
    const float* x        = (const float*)d_in[0];
    const float* alpha    = (const float*)d_in[1];
    const float* clusters = (const float*)d_in[2];
    const float* w1       = (const float*)d_in[3];
    const float* w2       = (const float*)d_in[4];
    const float* w3       = (const float*)d_in[5];
    float* out = (float*)d_out;
    float* ws  = (float*)d_ws;

    cl_refine_mm<<<dim3(27,3), dim3(384), 0, stream>>>(clusters, w1, w2, w3, ws);
    cl_adj<<<dim3(N_CL*N_CL), dim3(64), 0, stream>>>(ws, ws + WSF_ADJ);
    cl_graph2<<<dim3(1), dim3(1024), 0, stream>>>(ws, clusters, out);
    cl_mfma<<<dim3(NTILE), dim3(256), 0, stream>>>(x, alpha, (const ushort_t*)ws, ws, out);
    cl_final_reduce<<<dim3(1), dim3(1024), 0, stream>>>(ws, out);
}

// Round 10
// 136.635 us; speedup vs baseline: 2.7970x; 1.0020x over previous
//
#include <hip/hip_runtime.h>
#include <math.h>

#define N_CL   27
#define C_DIM  384
#define HW_SZ  6400
#define B_SZ   32
#define NPIX   (B_SZ*HW_SZ)        // 204800
#define NTILE  3200                 // 64-px tiles
#define NCHUNK 12                   // 384/32
#define WSF_PARTS 24576             // parts: [24576, 24576+6400)
#define WSF_ADJ   40000             // adj:   [40000, 40729)
#define ENT_OFF (1 + (size_t)NPIX*N_CL + (size_t)N_CL*C_DIM)

typedef unsigned short ushort_t;
using bf16x8 = __attribute__((ext_vector_type(8))) short;
using f32x4  = __attribute__((ext_vector_type(4))) float;

// XLA/Eigen fast-tanh f32 (FMA variant) — matches jax f32 reference semantics
__device__ __forceinline__ float xla_tanh_f32(float x) {
    const float c = 7.99881172180175781f;
    if (fabsf(x) < 0.0004f) return x;
    const float xc = fminf(fmaxf(x, -c), c);
    const float x2 = xc*xc;
    float p = fmaf(x2, -2.76076847742355e-16f, 2.00018790482477e-13f);
    p = fmaf(x2, p, -8.60467152213735e-11f);
    p = fmaf(x2, p,  5.12229709037114e-08f);
    p = fmaf(x2, p,  1.48572235717979e-05f);
    p = fmaf(x2, p,  6.37261928875436e-04f);
    p = fmaf(x2, p,  4.89352455891786e-03f);
    p = xc*p;
    float q = fmaf(x2, 1.19825839466702e-06f, 1.18534705686654e-04f);
    q = fmaf(x2, q, 2.26843463243900e-03f);
    q = fmaf(x2, q, 4.89352518554385e-03f);
    return p/q;
}

// ---------- kernel A: three 27x384 @ 384x384 matmuls ----------
__global__ __launch_bounds__(384) void cl_refine_mm(const float* __restrict__ clusters,
                                                    const float* __restrict__ w1,
                                                    const float* __restrict__ w2,
                                                    const float* __restrict__ w3,
                                                    float* __restrict__ ws) {
    const int i = blockIdx.x;
    const int m = blockIdx.y;
    const int j = threadIdx.x;
    __shared__ float crow[C_DIM];
    crow[j] = clusters[i*C_DIM + j];
    __syncthreads();
    const float* __restrict__ W = (m==0) ? w1 : (m==1) ? w2 : w3;
    float s0=0.f,s1=0.f,s2=0.f,s3=0.f;
    #pragma unroll 4
    for (int k=0;k<C_DIM;k+=4){
        s0 = fmaf(crow[k+0], W[(size_t)(k+0)*C_DIM + j], s0);
        s1 = fmaf(crow[k+1], W[(size_t)(k+1)*C_DIM + j], s1);
        s2 = fmaf(crow[k+2], W[(size_t)(k+2)*C_DIM + j], s2);
        s3 = fmaf(crow[k+3], W[(size_t)(k+3)*C_DIM + j], s3);
    }
    const float acc = (s0+s1)+(s2+s3);
    ws[(size_t)m*N_CL*C_DIM + i*C_DIM + j] = (m<2) ? xla_tanh_f32(3.0f*acc) : acc;
}

// ---------- kernel A2: adjacency entries, one (i,j) per 1-wave block ----------
__global__ __launch_bounds__(64) void cl_adj(const float* __restrict__ ws,
                                             float* __restrict__ adj_out) {
    const float* __restrict__ Am = ws;
    const float* __restrict__ Bm = ws + N_CL*C_DIM;
    const int i = blockIdx.x / N_CL, j = blockIdx.x - (blockIdx.x / N_CL)*N_CL;
    const int lane = threadIdx.x;
    float p=0.f, q=0.f;
    #pragma unroll
    for (int e=0;e<6;e++){
        const int k = e*64 + lane;
        p = fmaf(Am[i*C_DIM+k], Bm[j*C_DIM+k], p);
        q = fmaf(Bm[i*C_DIM+k], Am[j*C_DIM+k], q);
    }
    float d = p - q;     // i==j: p==q per-lane (identical order) -> exact 0
    #pragma unroll
    for (int m=1;m<64;m<<=1) d += __shfl_xor(d, m);
    if (lane==0) adj_out[blockIdx.x] = fmaxf(xla_tanh_f32(3.0f*d), 0.f);
}

// ---------- kernel B: top-k, GCN normalize, cl; pack W (bf16 hi/lo) ----------
__global__ __launch_bounds__(1024) void cl_graph2(float* ws,
                                                  const float* __restrict__ clusters_g,
                                                  float* __restrict__ out) {
    const float* cg = ws + 2*N_CL*C_DIM;
    float* cl_out = out + 1 + (size_t)NPIX*N_CL;
    const int t = threadIdx.x;

    __shared__ float anorm[N_CL][N_CL+1];
    __shared__ float dinv[N_CL];
    __shared__ float rinv[N_CL];
    __shared__ float cls[N_CL][C_DIM];

    if (t < N_CL*N_CL) {
        const int i = t / N_CL, j = t - (t / N_CL)*N_CL;
        anorm[i][j] = ws[WSF_ADJ + t];
    }
    __syncthreads();
    if (t < N_CL) {
        unsigned mask=0; float thr=0.f;
        for (int s=0;s<5;s++){
            float bv=-1.f; int bi2=0;
            for (int j=0;j<N_CL;j++){
                if (mask & (1u<<j)) continue;
                const float v = anorm[t][j];
                if (v > bv){ bv=v; bi2=j; }
            }
            mask |= 1u<<bi2; thr = bv;
        }
        float rs=0.f;
        for (int j=0;j<N_CL;j++){
            float v = anorm[t][j];
            v = (v >= thr) ? v : 0.f;
            if (j==t) v += 1.f;
            anorm[t][j] = v;
            rs += v;
        }
        dinv[t] = 1.0f / sqrtf(rs);
    }
    __syncthreads();
    if (t < N_CL*N_CL) {
        const int i = t / N_CL, j = t - (t / N_CL)*N_CL;
        anorm[i][j] = dinv[i]*anorm[i][j]*dinv[j];
    }
    __syncthreads();
    for (int idx=t; idx<N_CL*C_DIM; idx+=1024){
        const int i = idx / C_DIM, d = idx - i*C_DIM;
        float s=0.f;
        #pragma unroll
        for (int j=0;j<N_CL;j++) s = fmaf(anorm[i][j], cg[(size_t)j*C_DIM + d], s);
        cls[i][d] = s;
        cl_out[idx] = s;          // output 2: refined clusters
    }
    __syncthreads();
    if (t < N_CL) {
        float ssq=0.f;
        for (int d=0; d<C_DIM; d++){ const float v=cls[t][d]; ssq=fmaf(v,v,ssq); }
        rinv[t] = 1.0f / fmaxf(sqrtf(ssq), 1e-12f);
    }
    __syncthreads();
    // Pack: n<27 = normalized cl rows; 32<=n<59 = raw clusters; else 0.
    ushort_t* wpk = (ushort_t*)ws;
    for (int idx=t; idx<64*C_DIM; idx+=1024){
        const int n = idx / C_DIM, k = idx - n*C_DIM;
        float v = 0.f;
        if (n < N_CL) v = cls[n][k] * rinv[n];
        else if (n >= 32 && n < 32+N_CL) v = clusters_g[(size_t)(n-32)*C_DIM + k];
        const unsigned bits = __float_as_uint(v);
        const ushort_t hi = (ushort_t)(bits >> 16);
        const float lof = v - __uint_as_float(bits & 0xFFFF0000u);
        const ushort_t lo = (ushort_t)(__float_as_uint(lof) >> 16);
        wpk[idx] = hi;
        wpk[64*C_DIM + idx] = lo;
    }
}

// ---------- kernel C: A-in-register pipelined split-bf16 MFMA GEMM ----------
__global__ __launch_bounds__(256, 4) void cl_mfma(const float* __restrict__ x,
                                                  const float* __restrict__ alpha_p,
                                                  const ushort_t* __restrict__ wpk,
                                                  float* __restrict__ ws,
                                                  float* __restrict__ out) {
    __shared__ __align__(16) ushort_t lB[2][2][64][40]; // [buf][hi/lo][n][k] (B only)
    __shared__ float redL[4], redE[4];

    const int tid = threadIdx.x;
    const int blk = blockIdx.x;
    const int b   = blk / 100;
    const int hw0 = (blk - b*100) * 64;
    const float* __restrict__ xb = x + (size_t)b*C_DIM*HW_SZ + hw0;

    const int lane = tid & 63;
    const int w    = tid >> 6;
    const int l15  = lane & 15;
    const int g    = lane >> 4;
    const int k0   = g*8;
    const int apx  = w*16 + l15;
    const float* __restrict__ xl = xb + apx;   // this lane's pixel column

    // B staging decomposition
    const int b_n  = tid >> 2;           // 0..63
    const int b_kb = (tid & 3) * 8;

    uint4 rb0, rb1;
    #define LOADB(c) {                                                            \
        rb0 = *(const uint4*)(wpk + (size_t)(     b_n)*C_DIM + (c)*32 + b_kb);    \
        rb1 = *(const uint4*)(wpk + (size_t)(64 + b_n)*C_DIM + (c)*32 + b_kb); }
    #define WRITEB(bf) {                                                          \
        *(uint4*)(&lB[bf][0][b_n][b_kb]) = rb0;                                   \
        *(uint4*)(&lB[bf][1][b_n][b_kb]) = rb1; }

    // A: 8 regs per chunk, direct global->reg
    #define LOADA(c, R0,R1,R2,R3,R4,R5,R6,R7) {                                   \
        const float* pA = xl + (size_t)((c)*32 + k0)*HW_SZ;                       \
        R0 = pA[0*HW_SZ]; R1 = pA[1*HW_SZ]; R2 = pA[2*HW_SZ]; R3 = pA[3*HW_SZ];  \
        R4 = pA[4*HW_SZ]; R5 = pA[5*HW_SZ]; R6 = pA[6*HW_SZ]; R7 = pA[7*HW_SZ]; }

    union { ushort_t u[8]; bf16x8 v; } Ah, Al;
    float ss = 0.f;
    #define CVT1(e, R) {                                                          \
        const unsigned bits = __float_as_uint(R);                                 \
        Ah.u[e] = (ushort_t)(bits >> 16);                                         \
        const float lof = R - __uint_as_float(bits & 0xFFFF0000u);                \
        Al.u[e] = (ushort_t)(__float_as_uint(lof) >> 16);                         \
        ss = fmaf(R, R, ss); }
    #define CONVERT(R0,R1,R2,R3,R4,R5,R6,R7) {                                    \
        CVT1(0,R0) CVT1(1,R1) CVT1(2,R2) CVT1(3,R3)                               \
        CVT1(4,R4) CVT1(5,R5) CVT1(6,R6) CVT1(7,R7) }

    f32x4 acc0={0,0,0,0}, acc1={0,0,0,0}, acc2={0,0,0,0}, acc3={0,0,0,0};
    #define DOMFMA(cur) {                                                         \
        _Pragma("unroll")                                                         \
        for (int t = 0; t < 4; t++) {                                             \
            union { uint4 q; bf16x8 v; } Bh, Bl;                                  \
            Bh.q = *(const uint4*)(&lB[cur][0][t*16 + l15][k0]);                  \
            Bl.q = *(const uint4*)(&lB[cur][1][t*16 + l15][k0]);                  \
            f32x4 a = (t==0)?acc0:(t==1)?acc1:(t==2)?acc2:acc3;                   \
            a = __builtin_amdgcn_mfma_f32_16x16x32_bf16(Ah.v, Bh.v, a, 0,0,0);    \
            a = __builtin_amdgcn_mfma_f32_16x16x32_bf16(Ah.v, Bl.v, a, 0,0,0);    \
            a = __builtin_amdgcn_mfma_f32_16x16x32_bf16(Al.v, Bh.v, a, 0,0,0);    \
            if (t==0) acc0=a; else if (t==1) acc1=a; else if (t==2) acc2=a;       \
            else acc3=a;                                                          \
        } }

    float Ra0,Ra1,Ra2,Ra3,Ra4,Ra5,Ra6,Ra7;
    float Rb0,Rb1,Rb2,Rb3,Rb4,Rb5,Rb6,Rb7;

    LOADA(0, Ra0,Ra1,Ra2,Ra3,Ra4,Ra5,Ra6,Ra7);
    LOADB(0); WRITEB(0);
    LOADA(1, Rb0,Rb1,Rb2,Rb3,Rb4,Rb5,Rb6,Rb7);
    LOADB(1);
    __syncthreads();

    for (int cc = 0; cc < NCHUNK; cc += 2) {
        // even step: consume Ra + lB[0]
        CONVERT(Ra0,Ra1,Ra2,Ra3,Ra4,Ra5,Ra6,Ra7);
        if (cc + 2 < NCHUNK) LOADA(cc+2, Ra0,Ra1,Ra2,Ra3,Ra4,Ra5,Ra6,Ra7);
        DOMFMA(0);
        __syncthreads();
        WRITEB(1);                                // waits vmcnt for LOADB(cc+1)
        if (cc + 2 < NCHUNK) LOADB(cc+2);
        __syncthreads();
        // odd step: consume Rb + lB[1]
        CONVERT(Rb0,Rb1,Rb2,Rb3,Rb4,Rb5,Rb6,Rb7);
        if (cc + 3 < NCHUNK) LOADA(cc+3, Rb0,Rb1,Rb2,Rb3,Rb4,Rb5,Rb6,Rb7);
        DOMFMA(1);
        if (cc + 2 < NCHUNK) {
            __syncthreads();
            WRITEB(0);                            // waits vmcnt for LOADB(cc+2)
            if (cc + 3 < NCHUNK) LOADB(cc+3);
            __syncthreads();
        }
    }

    // full ||x||^2 per px
    ss += __shfl_xor(ss, 16);
    ss += __shfl_xor(ss, 32);
    f32x4 invv;
    #pragma unroll
    for (int r = 0; r < 4; r++) {
        const float s2 = __shfl(ss, g*4 + r);
        invv[r] = 1.0f / fmaxf(sqrtf(s2), 1e-12f);
    }

    const float alpha = alpha_p[0];
    float* __restrict__ out1 = out + 1;
    const int pxb = hw0 + w*16 + g*4;

    f32x4 st0, st1;
    #pragma unroll
    for (int r=0;r<4;r++){ st0[r] = acc0[r]*invv[r]; st1[r] = acc1[r]*invv[r]; }
    *(f32x4*)(out1 + (size_t)b*N_CL*HW_SZ + (size_t)l15*HW_SZ + pxb) = st0;
    if (l15 <= 10)
        *(f32x4*)(out1 + (size_t)b*N_CL*HW_SZ + (size_t)(16+l15)*HW_SZ + pxb) = st1;

    float wloss = 0.f, went = 0.f;
    #pragma unroll
    for (int r=0;r<4;r++){
        const float ip0 = st0[r], ip1 = st1[r];
        const float v0 = alpha*ip0;
        const float v1 = (l15<=10) ? alpha*ip1 : -INFINITY;
        float mx = fmaxf(v0, v1);
        #pragma unroll
        for (int m=1;m<16;m<<=1) mx = fmaxf(mx, __shfl_xor(mx, m));
        const float e0 = expf(v0 - mx);
        const float e1 = (l15<=10) ? expf(v1 - mx) : 0.f;
        float z = e0 + e1;
        float tt = fmaf(e0, ip0, (l15<=10) ? e1*ip1 : 0.f);
        #pragma unroll
        for (int m=1;m<16;m<<=1){ z += __shfl_xor(z,m); tt += __shfl_xor(tt,m); }
        wloss += tt/z;
        const float c0 = acc2[r];
        const float c1 = (l15<=10) ? acc3[r] : -INFINITY;
        float emx = fmaxf(c0, c1);
        #pragma unroll
        for (int m=1;m<16;m<<=1) emx = fmaxf(emx, __shfl_xor(emx, m));
        const float f0 = expf(c0 - emx);
        const float f1 = (l15<=10) ? expf(c1 - emx) : 0.f;
        float ez = f0 + f1;
        #pragma unroll
        for (int m=1;m<16;m<<=1) ez += __shfl_xor(ez,m);
        const float iz = 1.0f/ez;
        const float p0 = f0*iz, p1 = f1*iz;
        float te = -p0*logf(p0+1e-10f) - p1*logf(p1+1e-10f);
        #pragma unroll
        for (int m=1;m<16;m<<=1) te += __shfl_xor(te,m);
        went += te;
    }
    wloss += __shfl_xor(wloss,16); wloss += __shfl_xor(wloss,32);
    went  += __shfl_xor(went ,16); went  += __shfl_xor(went ,32);
    if (lane == 0) { redL[w] = wloss; redE[w] = went; }
    __syncthreads();
    if (tid == 0) {
        float* parts = ws + WSF_PARTS;
        parts[blk]         = redL[0]+redL[1]+redL[2]+redL[3];
        parts[NTILE + blk] = redE[0]+redE[1]+redE[2]+redE[3];
    }
}

// ---------- kernel D: final deterministic reduction ----------
__global__ __launch_bounds__(1024) void cl_final_reduce(const float* __restrict__ ws,
                                                        float* __restrict__ out) {
    __shared__ float r[1024];
    const int t = threadIdx.x;
    const float* parts = ws + WSF_PARTS;
    float s = 0.f;
    for (int j=t; j<NTILE; j+=1024) s += parts[j];
    r[t] = s; __syncthreads();
    for (int sft=512;sft>0;sft>>=1){ if (t<sft) r[t]+=r[t+sft]; __syncthreads(); }
    if (t==0) out[0] = -r[0]*(1.0f/NPIX);
    __syncthreads();
    s = 0.f;
    for (int j=t; j<NTILE; j+=1024) s += parts[NTILE + j];
    r[t] = s; __syncthreads();
    for (int sft=512;sft>0;sft>>=1){ if (t<sft) r[t]+=r[t+sft]; __syncthreads(); }
    if (t==0) out[ENT_OFF] = r[0]*(1.0f/NPIX);
}

extern "C" void kernel_launch(void* const* d_in, const int* in_sizes, int n_in,
                              void* d_out, int out_size, void* d_ws, size_t ws_size,
                              hipStream_t stream) {
    const float* x        = (const float*)d_in[0];
    const float* alpha    = (const float*)d_in[1];
    const float* clusters = (const float*)d_in[2];
    const float* w1       = (const float*)d_in[3];
    const float* w2       = (const float*)d_in[4];
    const float* w3       = (const float*)d_in[5];
    float* out = (float*)d_out;
    float* ws  = (float*)d_ws;

    cl_refine_mm<<<dim3(27,3), dim3(384), 0, stream>>>(clusters, w1, w2, w3, ws);
    cl_adj<<<dim3(N_CL*N_CL), dim3(64), 0, stream>>>(ws, ws + WSF_ADJ);
    cl_graph2<<<dim3(1), dim3(1024), 0, stream>>>(ws, clusters, out);
    cl_mfma<<<dim3(NTILE), dim3(256), 0, stream>>>(x, alpha, (const ushort_t*)ws, ws, out);
    cl_final_reduce<<<dim3(1), dim3(1024), 0, stream>>>(ws, out);
}